// Round 1
// baseline (1451.963 us; speedup 1.0000x reference)
//
#include <hip/hip_runtime.h>
#include <hip/hip_bf16.h>
#include <math.h>

typedef unsigned short u16;
typedef unsigned int u32;

#define N_NODES 50000
#define N_EDGES 1600000
#define DIM     512
#define DOUT    40
#define MPAD    50048   // 391 * 128

typedef __bf16 bf16x8 __attribute__((ext_vector_type(8)));
typedef float  f32x4  __attribute__((ext_vector_type(4)));

__device__ inline float bf2f(u16 u) {
    union { u32 i; float f; } v; v.i = ((u32)u) << 16; return v.f;
}
__device__ inline u16 f2bf(float f) {
    union { float f; u32 u; } v; v.f = f;
    u32 u = v.u;
    u32 r = u + 0x7fffu + ((u >> 16) & 1u);   // RNE
    return (u16)(r >> 16);
}
__device__ inline float2 bfpair(u32 u) {
    float2 r;
    union { u32 i; float f; } lo, hi;
    lo.i = u << 16; hi.i = u & 0xffff0000u;
    r.x = lo.f; r.y = hi.f; return r;
}
__device__ inline float wave_sum(float v) {
    #pragma unroll
    for (int o = 32; o > 0; o >>= 1) v += __shfl_xor(v, o);
    return v;
}
__device__ inline float wave_max(float v) {
    #pragma unroll
    for (int o = 32; o > 0; o >>= 1) v = fmaxf(v, __shfl_xor(v, o));
    return v;
}

// ---------------- x f32 -> bf16 (padded rows zeroed) ----------------
__global__ __launch_bounds__(256) void k_conv_x(const float* __restrict__ x,
                                                u16* __restrict__ xb) {
    long idx = (long)blockIdx.x * 256 + threadIdx.x;
    long base = idx * 4;
    if (base >= (long)MPAD * DIM) return;
    long row = base >> 9;  // /512
    float4 v;
    if (row < N_NODES) v = *(const float4*)(x + base);
    else { v.x = v.y = v.z = v.w = 0.f; }
    ushort4 o;
    o.x = f2bf(v.x); o.y = f2bf(v.y); o.z = f2bf(v.z); o.w = f2bf(v.w);
    *(ushort4*)(xb + base) = o;
}

// ---------------- weight transposes ----------------
__global__ __launch_bounds__(256) void k_transpose_bf16(const float* __restrict__ W,
                                                        u16* __restrict__ Wt,
                                                        int K, int N) {
    int n = blockIdx.x * 16 + threadIdx.x;
    int k = blockIdx.y * 16 + threadIdx.y;
    if (k < K && n < N) Wt[(long)n * K + k] = f2bf(W[(long)k * N + n]);
}
__global__ __launch_bounds__(256) void k_transpose_f32(const float* __restrict__ W,
                                                       float* __restrict__ Wt,
                                                       int K, int N) {
    int n = blockIdx.x * 16 + threadIdx.x;
    int k = blockIdx.y * 16 + threadIdx.y;
    if (k < K && n < N) Wt[(long)n * K + k] = W[(long)k * N + n];
}

// ---------------- degree / dinv ----------------
__global__ __launch_bounds__(256) void k_deg(const int* __restrict__ esrc, int* __restrict__ deg) {
    int e = blockIdx.x * 256 + threadIdx.x;
    if (e < N_EDGES) atomicAdd(&deg[esrc[e]], 1);
}
__global__ __launch_bounds__(256) void k_dinv(const int* __restrict__ deg, float* __restrict__ dinv) {
    int i = blockIdx.x * 256 + threadIdx.x;
    if (i < N_NODES) {
        int d = deg[i];
        dinv[i] = (d > 0) ? (1.0f / sqrtf((float)d)) : 0.0f;
    }
}

// ---------------- bf16 MFMA GEMM: out = epilogue(A @ Bt^T) ----------------
// A [MPAD][512] bf16, Bt [512(n)][512(k)] bf16. 128x128 tile, 4 waves, BK=64.
// EPI 0: out = bf16(relu(acc + bias))                              (layer-in GEMM)
// EPI 1: out = bf16(bn((relu(acc + bias))))                        (classifier GEMM)
template<int EPI>
__global__ __launch_bounds__(256) void k_gemm(const u16* __restrict__ A,
                                              const u16* __restrict__ Bt,
                                              u16* __restrict__ outB,
                                              const float* __restrict__ bias,
                                              const float* __restrict__ bn_g,
                                              const float* __restrict__ bn_b,
                                              const float* __restrict__ bn_mean,
                                              const float* __restrict__ bn_var) {
    __shared__ u16 lds[2 * 128 * 64];  // 32 KB: A tile then B tile
    char* ldsA = (char*)lds;
    char* ldsB = (char*)lds + 16384;

    const int tid = threadIdx.x;
    const int tm = blockIdx.x, tn = blockIdx.y;
    const int l = tid & 63, wid = tid >> 6;
    const int wr = wid >> 1, wc = wid & 1;
    const int lm = l & 15, lk = l >> 4;

    const int srow0 = tid >> 3;            // staging row base (0..31)
    const int scole = (tid & 7) * 8;       // staging elem col (0..56)
    const int scolb = scole * 2;           // byte col

    f32x4 acc[4][4] = {};

    for (int kt = 0; kt < 8; ++kt) {
        const int k0 = kt * 64;
        #pragma unroll
        for (int r = 0; r < 4; ++r) {
            int row = r * 32 + srow0;
            uint4 va = *(const uint4*)(A + ((long)tm * 128 + row) * DIM + k0 + scole);
            *(uint4*)(ldsA + row * 128 + (scolb ^ ((row & 7) << 4))) = va;
            uint4 vb = *(const uint4*)(Bt + ((long)tn * 128 + row) * DIM + k0 + scole);
            *(uint4*)(ldsB + row * 128 + (scolb ^ ((row & 7) << 4))) = vb;
        }
        __syncthreads();
        #pragma unroll
        for (int kk = 0; kk < 2; ++kk) {
            bf16x8 af[4], bfr[4];
            #pragma unroll
            for (int m = 0; m < 4; ++m) {
                int ar = wr * 64 + m * 16 + lm;
                af[m] = *(const bf16x8*)(ldsA + ar * 128 + ((kk * 64 + lk * 16) ^ ((ar & 7) << 4)));
            }
            #pragma unroll
            for (int n = 0; n < 4; ++n) {
                int br = wc * 64 + n * 16 + lm;
                bfr[n] = *(const bf16x8*)(ldsB + br * 128 + ((kk * 64 + lk * 16) ^ ((br & 7) << 4)));
            }
            #pragma unroll
            for (int m = 0; m < 4; ++m)
                #pragma unroll
                for (int n = 0; n < 4; ++n)
                    acc[m][n] = __builtin_amdgcn_mfma_f32_16x16x32_bf16(af[m], bfr[n], acc[m][n], 0, 0, 0);
        }
        __syncthreads();
    }

    #pragma unroll
    for (int n = 0; n < 4; ++n) {
        int col = tn * 128 + wc * 64 + n * 16 + lm;
        float bc = bias[col];
        float scale = 0.f, shift = 0.f;
        if (EPI == 1) {
            scale = bn_g[col] / sqrtf(bn_var[col] + 1e-5f);
            shift = bn_b[col] - bn_mean[col] * scale;
        }
        #pragma unroll
        for (int m = 0; m < 4; ++m) {
            f32x4 v = acc[m][n];
            #pragma unroll
            for (int r = 0; r < 4; ++r) {
                long row = (long)tm * 128 + wr * 64 + m * 16 + lk * 4 + r;
                float val = fmaxf(v[r] + bc, 0.f);
                if (EPI == 1) val = val * scale + shift;
                outB[row * DIM + col] = f2bf(val);
            }
        }
    }
}

// ---------------- LayerNorm (in-place on hb) + row-norm + hn ----------------
// wave per row; pad rows get zeroed hb.
__global__ __launch_bounds__(256) void k_ln(u16* __restrict__ hb,
                                            u16* __restrict__ hn,
                                            const float* __restrict__ g,
                                            const float* __restrict__ b,
                                            float* __restrict__ a0,
                                            float* __restrict__ a1,
                                            float* __restrict__ inv_nrm) {
    int row = blockIdx.x * 4 + (threadIdx.x >> 6);
    int l = threadIdx.x & 63;
    u16* prow = hb + (long)row * DIM + l * 8;
    if (row >= N_NODES) {
        if (row < MPAD) { uint4 z; z.x = z.y = z.z = z.w = 0u; *(uint4*)prow = z; }
        return;
    }
    uint4 v = *(const uint4*)prow;
    float x[8];
    { float2 p;
      p = bfpair(v.x); x[0] = p.x; x[1] = p.y;
      p = bfpair(v.y); x[2] = p.x; x[3] = p.y;
      p = bfpair(v.z); x[4] = p.x; x[5] = p.y;
      p = bfpair(v.w); x[6] = p.x; x[7] = p.y; }
    float s = 0.f, sq = 0.f;
    #pragma unroll
    for (int j = 0; j < 8; ++j) { s += x[j]; sq += x[j] * x[j]; }
    #pragma unroll
    for (int o = 32; o > 0; o >>= 1) { s += __shfl_xor(s, o); sq += __shfl_xor(sq, o); }
    float mean = s * (1.f / DIM);
    float var = sq * (1.f / DIM) - mean * mean;
    float rstd = 1.f / sqrtf(var + 1e-5f);
    float y[8];
    #pragma unroll
    for (int j = 0; j < 8; ++j) {
        int c = l * 8 + j;
        y[j] = (x[j] - mean) * rstd * g[c] + b[c];
    }
    float s2 = 0.f;
    #pragma unroll
    for (int j = 0; j < 8; ++j) s2 += y[j] * y[j];
    s2 = wave_sum(s2);
    float nrm = sqrtf(s2);
    float inv = 1.f / (nrm + 1e-4f);
    ushort4 oh, on;
    oh.x = f2bf(y[0]); oh.y = f2bf(y[1]); oh.z = f2bf(y[2]); oh.w = f2bf(y[3]);
    *(ushort4*)prow = oh;
    oh.x = f2bf(y[4]); oh.y = f2bf(y[5]); oh.z = f2bf(y[6]); oh.w = f2bf(y[7]);
    *(ushort4*)(prow + 4) = oh;
    u16* nrow = hn + (long)row * DIM + l * 8;
    on.x = f2bf(y[0] * inv); on.y = f2bf(y[1] * inv); on.z = f2bf(y[2] * inv); on.w = f2bf(y[3] * inv);
    *(ushort4*)nrow = on;
    on.x = f2bf(y[4] * inv); on.y = f2bf(y[5] * inv); on.z = f2bf(y[6] * inv); on.w = f2bf(y[7] * inv);
    *(ushort4*)(nrow + 4) = on;
    if (l == 0) { a0[row] = y[0]; a1[row] = y[1]; inv_nrm[row] = inv; }
}

// ---------------- one-time per-edge partial dot over dims 2..511 ----------------
// wave per edge; rest[e] = sum_{d>=2} hn[s][d]*hn[d][d]
__global__ __launch_bounds__(256) void k_edge_dot(const int* __restrict__ esrc,
                                                  const int* __restrict__ edst,
                                                  const u16* __restrict__ hn,
                                                  float* __restrict__ rest) {
    int e = blockIdx.x * 4 + (threadIdx.x >> 6);
    if (e >= N_EDGES) return;
    int l = threadIdx.x & 63;
    int s = esrc[e], d = edst[e];
    uint4 sv = *(const uint4*)(hn + (long)s * DIM + l * 8);
    uint4 dv = *(const uint4*)(hn + (long)d * DIM + l * 8);
    float acc;
    {
        float2 a = bfpair(sv.x), b = bfpair(dv.x);
        float p0 = a.x * b.x, p1 = a.y * b.y;
        if (l == 0) { p0 = 0.f; p1 = 0.f; }   // exclude dims 0,1
        acc = p0 + p1;
    }
    { float2 a = bfpair(sv.y), b = bfpair(dv.y); acc += a.x * b.x + a.y * b.y; }
    { float2 a = bfpair(sv.z), b = bfpair(dv.z); acc += a.x * b.x + a.y * b.y; }
    { float2 a = bfpair(sv.w), b = bfpair(dv.w); acc += a.x * b.x + a.y * b.y; }
    acc = wave_sum(acc);
    if (l == 0) rest[e] = acc;
}

// ---------------- per-layer: delta[s] += dinv[d] * clip(cos_e) ----------------
__global__ __launch_bounds__(256) void k_delta(const int* __restrict__ esrc,
                                               const int* __restrict__ edst,
                                               const float* __restrict__ rest,
                                               const float* __restrict__ a0,
                                               const float* __restrict__ a1,
                                               const float* __restrict__ inv_nrm,
                                               const float* __restrict__ dinv,
                                               float* __restrict__ delta) {
    int e = blockIdx.x * 256 + threadIdx.x;
    if (e >= N_EDGES) return;
    int s = esrc[e], d = edst[e];
    float c = rest[e] + (a0[s] * a0[d] + a1[s] * a1[d]) * inv_nrm[s] * inv_nrm[d];
    c = fminf(1.f, fmaxf(-1.f, c));
    atomicAdd(&delta[s], dinv[d] * c);
}

// ---------------- per-layer: rotate (a0,a1), reset delta ----------------
__global__ __launch_bounds__(256) void k_rot(const float* __restrict__ dinv,
                                             float* __restrict__ delta,
                                             float* __restrict__ a0,
                                             float* __restrict__ a1) {
    int i = blockIdx.x * 256 + threadIdx.x;
    if (i >= N_NODES) return;
    float ang = dinv[i] * delta[i];
    float sn, cs;
    sincosf(ang, &sn, &cs);
    float x = a0[i], y = a1[i];
    a0[i] = cs * x - sn * y;
    a1[i] = sn * x + cs * y;
    delta[i] = 0.f;
}

// ---------------- write rotated dims back into hb ----------------
__global__ __launch_bounds__(256) void k_wb(const float* __restrict__ a0,
                                            const float* __restrict__ a1,
                                            u16* __restrict__ hb) {
    int i = blockIdx.x * 256 + threadIdx.x;
    if (i >= N_NODES) return;
    hb[(long)i * DIM + 0] = f2bf(a0[i]);
    hb[(long)i * DIM + 1] = f2bf(a1[i]);
}

// ---------------- logits + log_softmax (wave per row) ----------------
__global__ __launch_bounds__(256) void k_final(const u16* __restrict__ zb,
                                               const float* __restrict__ W2t,  // [40][512]
                                               const float* __restrict__ cb2,
                                               float* __restrict__ out) {
    __shared__ float zs[4][DIM];
    int w = threadIdx.x >> 6, l = threadIdx.x & 63;
    long row = (long)blockIdx.x * 4 + w;
    uint4 v = *(const uint4*)(zb + row * DIM + l * 8);
    float2 p;
    int c0 = l * 8;
    p = bfpair(v.x); zs[w][c0 + 0] = p.x; zs[w][c0 + 1] = p.y;
    p = bfpair(v.y); zs[w][c0 + 2] = p.x; zs[w][c0 + 3] = p.y;
    p = bfpair(v.z); zs[w][c0 + 4] = p.x; zs[w][c0 + 5] = p.y;
    p = bfpair(v.w); zs[w][c0 + 6] = p.x; zs[w][c0 + 7] = p.y;
    __syncthreads();
    float dot = 0.f;
    if (l < DOUT) {
        const float4* wrow = (const float4*)(W2t + (long)l * DIM);
        const float4* zr = (const float4*)(&zs[w][0]);
        #pragma unroll 4
        for (int d4 = 0; d4 < DIM / 4; ++d4) {
            float4 a = zr[d4], b = wrow[d4];
            dot += a.x * b.x + a.y * b.y + a.z * b.z + a.w * b.w;
        }
        dot += cb2[l];
    }
    float mv = (l < DOUT) ? dot : -1e30f;
    mv = wave_max(mv);
    float ex = (l < DOUT) ? expf(dot - mv) : 0.f;
    float ssum = wave_sum(ex);
    float lse = logf(ssum);
    if (l < DOUT) out[row * DOUT + l] = dot - mv - lse;
}

extern "C" void kernel_launch(void* const* d_in, const int* in_sizes, int n_in,
                              void* d_out, int out_size, void* d_ws, size_t ws_size,
                              hipStream_t stream) {
    const float* x       = (const float*)d_in[0];
    const int*   esrc    = (const int*)d_in[1];
    const int*   edst    = (const int*)d_in[2];
    const float* W_in    = (const float*)d_in[3];
    const float* b_in    = (const float*)d_in[4];
    const float* ln_g    = (const float*)d_in[5];
    const float* ln_b    = (const float*)d_in[6];
    const float* cW1     = (const float*)d_in[7];
    const float* cb1     = (const float*)d_in[8];
    const float* bn_g    = (const float*)d_in[9];
    const float* bn_b    = (const float*)d_in[10];
    const float* bn_mean = (const float*)d_in[11];
    const float* bn_var  = (const float*)d_in[12];
    const float* cW2     = (const float*)d_in[13];
    const float* cb2     = (const float*)d_in[14];
    float* out = (float*)d_out;

    char* ws = (char*)d_ws;
    size_t off = 0;
    auto take = [&](size_t bytes) -> char* {
        char* p = ws + off;
        off = (off + bytes + 255) & ~(size_t)255;
        return p;
    };
    u16*   xb   = (u16*)take((size_t)MPAD * DIM * 2);   // later reused as zb
    u16*   hb   = (u16*)take((size_t)MPAD * DIM * 2);
    u16*   hn   = (u16*)take((size_t)N_NODES * DIM * 2);
    u16*   WtIn = (u16*)take((size_t)512 * 512 * 2);
    u16*   W1t  = (u16*)take((size_t)512 * 512 * 2);
    float* W2t  = (float*)take((size_t)DOUT * 512 * 4);
    int*   deg  = (int*)take((size_t)N_NODES * 4);
    float* dinv = (float*)take((size_t)N_NODES * 4);
    float* a0   = (float*)take((size_t)N_NODES * 4);
    float* a1   = (float*)take((size_t)N_NODES * 4);
    float* invn = (float*)take((size_t)N_NODES * 4);
    float* dlt  = (float*)take((size_t)N_NODES * 4);
    float* rest = (float*)take((size_t)N_EDGES * 4);
    u16*   zb   = xb;

    hipMemsetAsync(deg, 0, (size_t)N_NODES * 4, stream);
    hipMemsetAsync(dlt, 0, (size_t)N_NODES * 4, stream);

    k_conv_x<<<(MPAD * DIM / 4 + 255) / 256, 256, 0, stream>>>(x, xb);
    k_transpose_bf16<<<dim3(32, 32), dim3(16, 16), 0, stream>>>(W_in, WtIn, 512, 512);
    k_transpose_bf16<<<dim3(32, 32), dim3(16, 16), 0, stream>>>(cW1, W1t, 512, 512);
    k_transpose_f32<<<dim3(3, 32), dim3(16, 16), 0, stream>>>(cW2, W2t, 512, DOUT);
    k_deg<<<N_EDGES / 256, 256, 0, stream>>>(esrc, deg);
    k_dinv<<<(N_NODES + 255) / 256, 256, 0, stream>>>(deg, dinv);

    k_gemm<0><<<dim3(MPAD / 128, 4), 256, 0, stream>>>(xb, WtIn, hb, b_in,
                                                       nullptr, nullptr, nullptr, nullptr);
    k_ln<<<MPAD / 4, 256, 0, stream>>>(hb, hn, ln_g, ln_b, a0, a1, invn);
    k_edge_dot<<<N_EDGES / 4, 256, 0, stream>>>(esrc, edst, hn, rest);

    for (int layer = 0; layer < 3; ++layer) {
        k_delta<<<N_EDGES / 256, 256, 0, stream>>>(esrc, edst, rest, a0, a1, invn, dinv, dlt);
        k_rot<<<(N_NODES + 255) / 256, 256, 0, stream>>>(dinv, dlt, a0, a1);
    }
    k_wb<<<(N_NODES + 255) / 256, 256, 0, stream>>>(a0, a1, hb);

    k_gemm<1><<<dim3(MPAD / 128, 4), 256, 0, stream>>>(hb, W1t, zb, cb1,
                                                       bn_g, bn_b, bn_mean, bn_var);
    k_final<<<N_NODES / 4, 256, 0, stream>>>(zb, W2t, cb2, out);
}

// Round 2
// 973.162 us; speedup vs baseline: 1.4920x; 1.4920x over previous
//
#include <hip/hip_runtime.h>
#include <hip/hip_bf16.h>
#include <math.h>

typedef unsigned short u16;
typedef unsigned int u32;

#define N_NODES 50000
#define N_EDGES 1600000
#define DIM     512
#define DOUT    40
#define MPAD    50048   // 391 * 128

typedef __bf16 bf16x8 __attribute__((ext_vector_type(8)));
typedef float  f32x4  __attribute__((ext_vector_type(4)));

__device__ inline float bf2f(u16 u) {
    union { u32 i; float f; } v; v.i = ((u32)u) << 16; return v.f;
}
__device__ inline u16 f2bf(float f) {
    union { float f; u32 u; } v; v.f = f;
    u32 u = v.u;
    u32 r = u + 0x7fffu + ((u >> 16) & 1u);   // RNE
    return (u16)(r >> 16);
}
__device__ inline float2 bfpair(u32 u) {
    float2 r;
    union { u32 i; float f; } lo, hi;
    lo.i = u << 16; hi.i = u & 0xffff0000u;
    r.x = lo.f; r.y = hi.f; return r;
}
__device__ inline float wave_sum(float v) {
    #pragma unroll
    for (int o = 32; o > 0; o >>= 1) v += __shfl_xor(v, o);
    return v;
}

// ---------------- x f32 -> bf16 (padded rows zeroed) ----------------
__global__ __launch_bounds__(256) void k_conv_x(const float* __restrict__ x,
                                                u16* __restrict__ xb) {
    long idx = (long)blockIdx.x * 256 + threadIdx.x;
    long base = idx * 4;
    if (base >= (long)MPAD * DIM) return;
    long row = base >> 9;  // /512
    float4 v;
    if (row < N_NODES) v = *(const float4*)(x + base);
    else { v.x = v.y = v.z = v.w = 0.f; }
    ushort4 o;
    o.x = f2bf(v.x); o.y = f2bf(v.y); o.z = f2bf(v.z); o.w = f2bf(v.w);
    *(ushort4*)(xb + base) = o;
}

// ---------------- weight transposes ----------------
__global__ __launch_bounds__(256) void k_transpose_bf16(const float* __restrict__ W,
                                                        u16* __restrict__ Wt,
                                                        int K, int N) {
    int n = blockIdx.x * 16 + threadIdx.x;
    int k = blockIdx.y * 16 + threadIdx.y;
    if (k < K && n < N) Wt[(long)n * K + k] = f2bf(W[(long)k * N + n]);
}
// cW2 [512][40] f32 -> W2b [48][512] bf16, rows 40..47 zeroed
__global__ __launch_bounds__(256) void k_prep_w2(const float* __restrict__ cW2,
                                                 u16* __restrict__ W2b) {
    int idx = blockIdx.x * 256 + threadIdx.x;   // 0 .. 48*512-1
    if (idx >= 48 * DIM) return;
    int n = idx >> 9;        // out col (0..47)
    int k = idx & 511;       // in dim
    float v = (n < DOUT) ? cW2[(long)k * DOUT + n] : 0.f;
    W2b[idx] = f2bf(v);
}

// ---------------- degree / dinv ----------------
__global__ __launch_bounds__(256) void k_deg(const int* __restrict__ esrc, int* __restrict__ deg) {
    int e = blockIdx.x * 256 + threadIdx.x;
    if (e < N_EDGES) atomicAdd(&deg[esrc[e]], 1);
}
__global__ __launch_bounds__(256) void k_dinv(const int* __restrict__ deg, float* __restrict__ dinv) {
    int i = blockIdx.x * 256 + threadIdx.x;
    if (i < N_NODES) {
        int d = deg[i];
        dinv[i] = (d > 0) ? (1.0f / sqrtf((float)d)) : 0.0f;
    }
}

// ---------------- bf16 MFMA GEMM: out = epilogue(A @ Bt^T) ----------------
template<int EPI>
__global__ __launch_bounds__(256) void k_gemm(const u16* __restrict__ A,
                                              const u16* __restrict__ Bt,
                                              u16* __restrict__ outB,
                                              const float* __restrict__ bias,
                                              const float* __restrict__ bn_g,
                                              const float* __restrict__ bn_b,
                                              const float* __restrict__ bn_mean,
                                              const float* __restrict__ bn_var) {
    __shared__ u16 lds[2 * 128 * 64];  // 32 KB: A tile then B tile
    char* ldsA = (char*)lds;
    char* ldsB = (char*)lds + 16384;

    const int tid = threadIdx.x;
    const int tm = blockIdx.x, tn = blockIdx.y;
    const int l = tid & 63, wid = tid >> 6;
    const int wr = wid >> 1, wc = wid & 1;
    const int lm = l & 15, lk = l >> 4;

    const int srow0 = tid >> 3;            // staging row base (0..31)
    const int scole = (tid & 7) * 8;       // staging elem col (0..56)
    const int scolb = scole * 2;           // byte col

    f32x4 acc[4][4] = {};

    for (int kt = 0; kt < 8; ++kt) {
        const int k0 = kt * 64;
        #pragma unroll
        for (int r = 0; r < 4; ++r) {
            int row = r * 32 + srow0;
            uint4 va = *(const uint4*)(A + ((long)tm * 128 + row) * DIM + k0 + scole);
            *(uint4*)(ldsA + row * 128 + (scolb ^ ((row & 7) << 4))) = va;
            uint4 vb = *(const uint4*)(Bt + ((long)tn * 128 + row) * DIM + k0 + scole);
            *(uint4*)(ldsB + row * 128 + (scolb ^ ((row & 7) << 4))) = vb;
        }
        __syncthreads();
        #pragma unroll
        for (int kk = 0; kk < 2; ++kk) {
            bf16x8 af[4], bfr[4];
            #pragma unroll
            for (int m = 0; m < 4; ++m) {
                int ar = wr * 64 + m * 16 + lm;
                af[m] = *(const bf16x8*)(ldsA + ar * 128 + ((kk * 64 + lk * 16) ^ ((ar & 7) << 4)));
            }
            #pragma unroll
            for (int n = 0; n < 4; ++n) {
                int br = wc * 64 + n * 16 + lm;
                bfr[n] = *(const bf16x8*)(ldsB + br * 128 + ((kk * 64 + lk * 16) ^ ((br & 7) << 4)));
            }
            #pragma unroll
            for (int m = 0; m < 4; ++m)
                #pragma unroll
                for (int n = 0; n < 4; ++n)
                    acc[m][n] = __builtin_amdgcn_mfma_f32_16x16x32_bf16(af[m], bfr[n], acc[m][n], 0, 0, 0);
        }
        __syncthreads();
    }

    #pragma unroll
    for (int n = 0; n < 4; ++n) {
        int col = tn * 128 + wc * 64 + n * 16 + lm;
        float bc = bias[col];
        float scale = 0.f, shift = 0.f;
        if (EPI == 1) {
            scale = bn_g[col] / sqrtf(bn_var[col] + 1e-5f);
            shift = bn_b[col] - bn_mean[col] * scale;
        }
        #pragma unroll
        for (int m = 0; m < 4; ++m) {
            f32x4 v = acc[m][n];
            #pragma unroll
            for (int r = 0; r < 4; ++r) {
                long row = (long)tm * 128 + wr * 64 + m * 16 + lk * 4 + r;
                float val = fmaxf(v[r] + bc, 0.f);
                if (EPI == 1) val = val * scale + shift;
                outB[row * DIM + col] = f2bf(val);
            }
        }
    }
}

// ---------------- LayerNorm (in-place on hb) + row-norm + hn ----------------
__global__ __launch_bounds__(256) void k_ln(u16* __restrict__ hb,
                                            u16* __restrict__ hn,
                                            const float* __restrict__ g,
                                            const float* __restrict__ b,
                                            float* __restrict__ a0,
                                            float* __restrict__ a1,
                                            float* __restrict__ inv_nrm) {
    int row = blockIdx.x * 4 + (threadIdx.x >> 6);
    int l = threadIdx.x & 63;
    u16* prow = hb + (long)row * DIM + l * 8;
    if (row >= N_NODES) {
        if (row < MPAD) { uint4 z; z.x = z.y = z.z = z.w = 0u; *(uint4*)prow = z; }
        return;
    }
    uint4 v = *(const uint4*)prow;
    float x[8];
    { float2 p;
      p = bfpair(v.x); x[0] = p.x; x[1] = p.y;
      p = bfpair(v.y); x[2] = p.x; x[3] = p.y;
      p = bfpair(v.z); x[4] = p.x; x[5] = p.y;
      p = bfpair(v.w); x[6] = p.x; x[7] = p.y; }
    float s = 0.f, sq = 0.f;
    #pragma unroll
    for (int j = 0; j < 8; ++j) { s += x[j]; sq += x[j] * x[j]; }
    #pragma unroll
    for (int o = 32; o > 0; o >>= 1) { s += __shfl_xor(s, o); sq += __shfl_xor(sq, o); }
    float mean = s * (1.f / DIM);
    float var = sq * (1.f / DIM) - mean * mean;
    float rstd = 1.f / sqrtf(var + 1e-5f);
    float y[8];
    #pragma unroll
    for (int j = 0; j < 8; ++j) {
        int c = l * 8 + j;
        y[j] = (x[j] - mean) * rstd * g[c] + b[c];
    }
    float s2 = 0.f;
    #pragma unroll
    for (int j = 0; j < 8; ++j) s2 += y[j] * y[j];
    s2 = wave_sum(s2);
    float nrm = sqrtf(s2);
    float inv = 1.f / (nrm + 1e-4f);
    ushort4 oh, on;
    oh.x = f2bf(y[0]); oh.y = f2bf(y[1]); oh.z = f2bf(y[2]); oh.w = f2bf(y[3]);
    *(ushort4*)prow = oh;
    oh.x = f2bf(y[4]); oh.y = f2bf(y[5]); oh.z = f2bf(y[6]); oh.w = f2bf(y[7]);
    *(ushort4*)(prow + 4) = oh;
    u16* nrow = hn + (long)row * DIM + l * 8;
    on.x = f2bf(y[0] * inv); on.y = f2bf(y[1] * inv); on.z = f2bf(y[2] * inv); on.w = f2bf(y[3] * inv);
    *(ushort4*)nrow = on;
    on.x = f2bf(y[4] * inv); on.y = f2bf(y[5] * inv); on.z = f2bf(y[6] * inv); on.w = f2bf(y[7] * inv);
    *(ushort4*)(nrow + 4) = on;
    if (l == 0) { a0[row] = y[0]; a1[row] = y[1]; inv_nrm[row] = inv; }
}

// ---------------- one-time per-edge partial dot over dims 2..511 ----------------
__global__ __launch_bounds__(256) void k_edge_dot(const int* __restrict__ esrc,
                                                  const int* __restrict__ edst,
                                                  const u16* __restrict__ hn,
                                                  float* __restrict__ rest) {
    int e = blockIdx.x * 4 + (threadIdx.x >> 6);
    if (e >= N_EDGES) return;
    int l = threadIdx.x & 63;
    int s = esrc[e], d = edst[e];
    uint4 sv = *(const uint4*)(hn + (long)s * DIM + l * 8);
    uint4 dv = *(const uint4*)(hn + (long)d * DIM + l * 8);
    float acc;
    {
        float2 a = bfpair(sv.x), b = bfpair(dv.x);
        float p0 = a.x * b.x, p1 = a.y * b.y;
        if (l == 0) { p0 = 0.f; p1 = 0.f; }   // exclude dims 0,1
        acc = p0 + p1;
    }
    { float2 a = bfpair(sv.y), b = bfpair(dv.y); acc += a.x * b.x + a.y * b.y; }
    { float2 a = bfpair(sv.z), b = bfpair(dv.z); acc += a.x * b.x + a.y * b.y; }
    { float2 a = bfpair(sv.w), b = bfpair(dv.w); acc += a.x * b.x + a.y * b.y; }
    acc = wave_sum(acc);
    if (l == 0) rest[e] = acc;
}

// ---------------- per-layer: delta[s] += dinv[d] * clip(cos_e) ----------------
__global__ __launch_bounds__(256) void k_delta(const int* __restrict__ esrc,
                                               const int* __restrict__ edst,
                                               const float* __restrict__ rest,
                                               const float* __restrict__ a0,
                                               const float* __restrict__ a1,
                                               const float* __restrict__ inv_nrm,
                                               const float* __restrict__ dinv,
                                               float* __restrict__ delta) {
    int e = blockIdx.x * 256 + threadIdx.x;
    if (e >= N_EDGES) return;
    int s = esrc[e], d = edst[e];
    float c = rest[e] + (a0[s] * a0[d] + a1[s] * a1[d]) * inv_nrm[s] * inv_nrm[d];
    c = fminf(1.f, fmaxf(-1.f, c));
    atomicAdd(&delta[s], dinv[d] * c);
}

// ---------------- per-layer: rotate (a0,a1), reset delta ----------------
__global__ __launch_bounds__(256) void k_rot(const float* __restrict__ dinv,
                                             float* __restrict__ delta,
                                             float* __restrict__ a0,
                                             float* __restrict__ a1) {
    int i = blockIdx.x * 256 + threadIdx.x;
    if (i >= N_NODES) return;
    float ang = dinv[i] * delta[i];
    float sn, cs;
    sincosf(ang, &sn, &cs);
    float x = a0[i], y = a1[i];
    a0[i] = cs * x - sn * y;
    a1[i] = sn * x + cs * y;
    delta[i] = 0.f;
}

// ---------------- write rotated dims back into hb ----------------
__global__ __launch_bounds__(256) void k_wb(const float* __restrict__ a0,
                                            const float* __restrict__ a1,
                                            u16* __restrict__ hb) {
    int i = blockIdx.x * 256 + threadIdx.x;
    if (i >= N_NODES) return;
    hb[(long)i * DIM + 0] = f2bf(a0[i]);
    hb[(long)i * DIM + 1] = f2bf(a1[i]);
}

// ---------------- final: logits (MFMA skinny GEMM) + log_softmax ----------------
// zb [MPAD][512] bf16  @  W2b^T ([48][512] bf16, rows 40..47 zero) -> out [N][40] f32
// block = 256 threads = 4 waves; each wave computes 32 rows x 48 cols.
__global__ __launch_bounds__(256) void k_final(const u16* __restrict__ zb,
                                               const u16* __restrict__ W2b,
                                               const float* __restrict__ cb2,
                                               float* __restrict__ out) {
    __shared__ char ldsB[48 * 1024];   // 48 KB, XOR-swizzled rows
    const int tid = threadIdx.x;
    #pragma unroll
    for (int i = 0; i < 12; ++i) {
        int unit = i * 256 + tid;          // 3072 x 16B units
        int byte = unit * 16;
        int row = byte >> 10;
        int colb = byte & 1023;
        uint4 v = *(const uint4*)((const char*)W2b + byte);
        *(uint4*)(ldsB + row * 1024 + (colb ^ ((row & 7) << 4))) = v;
    }
    __syncthreads();

    const int l = tid & 63, wid = tid >> 6;
    const int lm = l & 15, lk = l >> 4;
    const long m0 = (long)blockIdx.x * 128 + wid * 32;

    f32x4 acc[2][3] = {};
    for (int kt = 0; kt < 16; ++kt) {
        const int k0 = kt * 32;
        bf16x8 af[2], bfr[3];
        #pragma unroll
        for (int m = 0; m < 2; ++m)
            af[m] = *(const bf16x8*)(zb + (m0 + m * 16 + lm) * DIM + k0 + lk * 8);
        #pragma unroll
        for (int n = 0; n < 3; ++n) {
            int br = n * 16 + lm;
            bfr[n] = *(const bf16x8*)(ldsB + br * 1024 + ((k0 * 2 + lk * 16) ^ ((br & 7) << 4)));
        }
        #pragma unroll
        for (int m = 0; m < 2; ++m)
            #pragma unroll
            for (int n = 0; n < 3; ++n)
                acc[m][n] = __builtin_amdgcn_mfma_f32_16x16x32_bf16(af[m], bfr[n], acc[m][n], 0, 0, 0);
    }

    // bias per n-column (col = n*16 + lm)
    float bc[3];
    #pragma unroll
    for (int n = 0; n < 3; ++n) {
        int col = n * 16 + lm;
        bc[n] = (col < DOUT) ? cb2[col] : 0.f;
    }

    // per-row log-softmax: row's 16 cols live in one 16-lane group (same lk)
    #pragma unroll
    for (int m = 0; m < 2; ++m) {
        #pragma unroll
        for (int r = 0; r < 4; ++r) {
            long row = m0 + m * 16 + lk * 4 + r;
            float v[3];
            float mv = -1e30f;
            #pragma unroll
            for (int n = 0; n < 3; ++n) {
                int col = n * 16 + lm;
                float t = (col < DOUT) ? (acc[m][n][r] + bc[n]) : -1e30f;
                v[n] = t;
                mv = fmaxf(mv, t);
            }
            #pragma unroll
            for (int o = 8; o > 0; o >>= 1) mv = fmaxf(mv, __shfl_xor(mv, o));
            float es = 0.f;
            #pragma unroll
            for (int n = 0; n < 3; ++n) {
                int col = n * 16 + lm;
                if (col < DOUT) es += expf(v[n] - mv);
            }
            #pragma unroll
            for (int o = 8; o > 0; o >>= 1) es += __shfl_xor(es, o);
            float lse = logf(es);
            if (row < N_NODES) {
                #pragma unroll
                for (int n = 0; n < 3; ++n) {
                    int col = n * 16 + lm;
                    if (col < DOUT) out[row * DOUT + col] = v[n] - mv - lse;
                }
            }
        }
    }
}

extern "C" void kernel_launch(void* const* d_in, const int* in_sizes, int n_in,
                              void* d_out, int out_size, void* d_ws, size_t ws_size,
                              hipStream_t stream) {
    const float* x       = (const float*)d_in[0];
    const int*   esrc    = (const int*)d_in[1];
    const int*   edst    = (const int*)d_in[2];
    const float* W_in    = (const float*)d_in[3];
    const float* b_in    = (const float*)d_in[4];
    const float* ln_g    = (const float*)d_in[5];
    const float* ln_b    = (const float*)d_in[6];
    const float* cW1     = (const float*)d_in[7];
    const float* cb1     = (const float*)d_in[8];
    const float* bn_g    = (const float*)d_in[9];
    const float* bn_b    = (const float*)d_in[10];
    const float* bn_mean = (const float*)d_in[11];
    const float* bn_var  = (const float*)d_in[12];
    const float* cW2     = (const float*)d_in[13];
    const float* cb2     = (const float*)d_in[14];
    float* out = (float*)d_out;

    char* ws = (char*)d_ws;
    size_t off = 0;
    auto take = [&](size_t bytes) -> char* {
        char* p = ws + off;
        off = (off + bytes + 255) & ~(size_t)255;
        return p;
    };
    u16*   xb   = (u16*)take((size_t)MPAD * DIM * 2);   // later reused as zb
    u16*   hb   = (u16*)take((size_t)MPAD * DIM * 2);
    u16*   hn   = (u16*)take((size_t)N_NODES * DIM * 2);
    u16*   WtIn = (u16*)take((size_t)512 * 512 * 2);
    u16*   W1t  = (u16*)take((size_t)512 * 512 * 2);
    u16*   W2b  = (u16*)take((size_t)48 * 512 * 2);
    int*   deg  = (int*)take((size_t)N_NODES * 4);
    float* dinv = (float*)take((size_t)N_NODES * 4);
    float* a0   = (float*)take((size_t)N_NODES * 4);
    float* a1   = (float*)take((size_t)N_NODES * 4);
    float* invn = (float*)take((size_t)N_NODES * 4);
    float* dlt  = (float*)take((size_t)N_NODES * 4);
    float* rest = (float*)take((size_t)N_EDGES * 4);
    u16*   zb   = xb;

    hipMemsetAsync(deg, 0, (size_t)N_NODES * 4, stream);
    hipMemsetAsync(dlt, 0, (size_t)N_NODES * 4, stream);

    k_conv_x<<<(MPAD * DIM / 4 + 255) / 256, 256, 0, stream>>>(x, xb);
    k_transpose_bf16<<<dim3(32, 32), dim3(16, 16), 0, stream>>>(W_in, WtIn, 512, 512);
    k_transpose_bf16<<<dim3(32, 32), dim3(16, 16), 0, stream>>>(cW1, W1t, 512, 512);
    k_prep_w2<<<(48 * DIM + 255) / 256, 256, 0, stream>>>(cW2, W2b);
    k_deg<<<N_EDGES / 256, 256, 0, stream>>>(esrc, deg);
    k_dinv<<<(N_NODES + 255) / 256, 256, 0, stream>>>(deg, dinv);

    k_gemm<0><<<dim3(MPAD / 128, 4), 256, 0, stream>>>(xb, WtIn, hb, b_in,
                                                       nullptr, nullptr, nullptr, nullptr);
    k_ln<<<MPAD / 4, 256, 0, stream>>>(hb, hn, ln_g, ln_b, a0, a1, invn);
    k_edge_dot<<<N_EDGES / 4, 256, 0, stream>>>(esrc, edst, hn, rest);

    for (int layer = 0; layer < 3; ++layer) {
        k_delta<<<N_EDGES / 256, 256, 0, stream>>>(esrc, edst, rest, a0, a1, invn, dinv, dlt);
        k_rot<<<(N_NODES + 255) / 256, 256, 0, stream>>>(dinv, dlt, a0, a1);
    }
    k_wb<<<(N_NODES + 255) / 256, 256, 0, stream>>>(a0, a1, hb);

    k_gemm<1><<<dim3(MPAD / 128, 4), 256, 0, stream>>>(hb, W1t, zb, cb1,
                                                       bn_g, bn_b, bn_mean, bn_var);
    k_final<<<MPAD / 128, 256, 0, stream>>>(zb, W2b, cb2, out);
}

// Round 3
// 678.986 us; speedup vs baseline: 2.1384x; 1.4333x over previous
//
#include <hip/hip_runtime.h>
#include <hip/hip_bf16.h>
#include <math.h>

typedef unsigned short u16;
typedef unsigned int u32;

#define N_NODES 50000
#define N_EDGES 1600000
#define DIM     512
#define DOUT    40
#define MPAD    50048   // 391 * 128
#define NBLK    196     // ceil(N_NODES/256)

typedef __bf16 bf16x8 __attribute__((ext_vector_type(8)));
typedef float  f32x4  __attribute__((ext_vector_type(4)));

__device__ inline float bf2f(u16 u) {
    union { u32 i; float f; } v; v.i = ((u32)u) << 16; return v.f;
}
__device__ inline u16 f2bf(float f) {
    union { float f; u32 u; } v; v.f = f;
    u32 u = v.u;
    u32 r = u + 0x7fffu + ((u >> 16) & 1u);   // RNE
    return (u16)(r >> 16);
}
__device__ inline float2 bfpair(u32 u) {
    float2 r;
    union { u32 i; float f; } lo, hi;
    lo.i = u << 16; hi.i = u & 0xffff0000u;
    r.x = lo.f; r.y = hi.f; return r;
}
__device__ inline float wave_sum(float v) {
    #pragma unroll
    for (int o = 32; o > 0; o >>= 1) v += __shfl_xor(v, o);
    return v;
}
__device__ inline int wave_sum_i(int v) {
    #pragma unroll
    for (int o = 32; o > 0; o >>= 1) v += __shfl_xor(v, o);
    return v;
}
// inclusive scan over a 256-thread block
__device__ inline int block_incl_scan(int v, int tid) {
    int lane = tid & 63, w = tid >> 6;
    #pragma unroll
    for (int o = 1; o < 64; o <<= 1) {
        int t = __shfl_up(v, o);
        if (lane >= o) v += t;
    }
    __shared__ int wsum[4];
    if (lane == 63) wsum[w] = v;
    __syncthreads();
    if (w > 0) v += wsum[0];
    if (w > 1) v += wsum[1];
    if (w > 2) v += wsum[2];
    return v;
}

// ---------------- x f32 -> bf16 (padded rows zeroed) ----------------
__global__ __launch_bounds__(256) void k_conv_x(const float* __restrict__ x,
                                                u16* __restrict__ xb) {
    long idx = (long)blockIdx.x * 256 + threadIdx.x;
    long base = idx * 4;
    if (base >= (long)MPAD * DIM) return;
    long row = base >> 9;  // /512
    float4 v;
    if (row < N_NODES) v = *(const float4*)(x + base);
    else { v.x = v.y = v.z = v.w = 0.f; }
    ushort4 o;
    o.x = f2bf(v.x); o.y = f2bf(v.y); o.z = f2bf(v.z); o.w = f2bf(v.w);
    *(ushort4*)(xb + base) = o;
}

// ---------------- weight transposes ----------------
__global__ __launch_bounds__(256) void k_transpose_bf16(const float* __restrict__ W,
                                                        u16* __restrict__ Wt,
                                                        int K, int N) {
    int n = blockIdx.x * 16 + threadIdx.x;
    int k = blockIdx.y * 16 + threadIdx.y;
    if (k < K && n < N) Wt[(long)n * K + k] = f2bf(W[(long)k * N + n]);
}
// cW2 [512][40] f32 -> W2b [48][512] bf16, rows 40..47 zeroed
__global__ __launch_bounds__(256) void k_prep_w2(const float* __restrict__ cW2,
                                                 u16* __restrict__ W2b) {
    int idx = blockIdx.x * 256 + threadIdx.x;   // 0 .. 48*512-1
    if (idx >= 48 * DIM) return;
    int n = idx >> 9;        // out col (0..47)
    int k = idx & 511;       // in dim
    float v = (n < DOUT) ? cW2[(long)k * DOUT + n] : 0.f;
    W2b[idx] = f2bf(v);
}

// ---------------- degree / dinv ----------------
__global__ __launch_bounds__(256) void k_deg(const int* __restrict__ esrc, int* __restrict__ deg) {
    int e = blockIdx.x * 256 + threadIdx.x;
    if (e < N_EDGES) atomicAdd(&deg[esrc[e]], 1);
}
__global__ __launch_bounds__(256) void k_dinv(const int* __restrict__ deg, float* __restrict__ dinv) {
    int i = blockIdx.x * 256 + threadIdx.x;
    if (i < N_NODES) {
        int d = deg[i];
        dinv[i] = (d > 0) ? (1.0f / sqrtf((float)d)) : 0.0f;
    }
}

// ---------------- CSR build: psum -> pbase -> rowptr -> scatter ----------------
__global__ __launch_bounds__(256) void k_csr_partial(const int* __restrict__ deg,
                                                     int* __restrict__ psum) {
    int idx = blockIdx.x * 256 + threadIdx.x;
    int v = (idx < N_NODES) ? deg[idx] : 0;
    int t = wave_sum_i(v);
    __shared__ int ws[4];
    int lane = threadIdx.x & 63, w = threadIdx.x >> 6;
    if (lane == 0) ws[w] = t;
    __syncthreads();
    if (threadIdx.x == 0) psum[blockIdx.x] = ws[0] + ws[1] + ws[2] + ws[3];
}
__global__ __launch_bounds__(256) void k_csr_base(const int* __restrict__ psum,
                                                  int* __restrict__ pbase,
                                                  int* __restrict__ rowptr) {
    int tid = threadIdx.x;
    int v = (tid < NBLK) ? psum[tid] : 0;
    int incl = block_incl_scan(v, tid);
    if (tid < NBLK) pbase[tid] = incl - v;   // exclusive
    if (tid == 0) rowptr[N_NODES] = N_EDGES;
}
__global__ __launch_bounds__(256) void k_csr_rowptr(const int* __restrict__ deg,
                                                    const int* __restrict__ pbase,
                                                    int* __restrict__ rowptr,
                                                    int* __restrict__ cnt) {
    int idx = blockIdx.x * 256 + threadIdx.x;
    int v = (idx < N_NODES) ? deg[idx] : 0;
    int incl = block_incl_scan(v, threadIdx.x);
    if (idx < N_NODES) {
        rowptr[idx] = pbase[blockIdx.x] + incl - v;
        cnt[idx] = 0;
    }
}
__global__ __launch_bounds__(256) void k_scatter(const int* __restrict__ esrc,
                                                 const int* __restrict__ edst,
                                                 const int* __restrict__ rowptr,
                                                 int* __restrict__ cnt,
                                                 int* __restrict__ edst_s) {
    int e = blockIdx.x * 256 + threadIdx.x;
    if (e >= N_EDGES) return;
    int s = esrc[e];
    int pos = rowptr[s] + atomicAdd(&cnt[s], 1);
    edst_s[pos] = edst[e];
}

// ---------------- bf16 MFMA GEMM: out = epilogue(A @ Bt^T) ----------------
template<int EPI>
__global__ __launch_bounds__(256) void k_gemm(const u16* __restrict__ A,
                                              const u16* __restrict__ Bt,
                                              u16* __restrict__ outB,
                                              const float* __restrict__ bias,
                                              const float* __restrict__ bn_g,
                                              const float* __restrict__ bn_b,
                                              const float* __restrict__ bn_mean,
                                              const float* __restrict__ bn_var) {
    __shared__ u16 lds[2 * 128 * 64];  // 32 KB: A tile then B tile
    char* ldsA = (char*)lds;
    char* ldsB = (char*)lds + 16384;

    const int tid = threadIdx.x;
    const int tm = blockIdx.x, tn = blockIdx.y;
    const int l = tid & 63, wid = tid >> 6;
    const int wr = wid >> 1, wc = wid & 1;
    const int lm = l & 15, lk = l >> 4;

    const int srow0 = tid >> 3;            // staging row base (0..31)
    const int scole = (tid & 7) * 8;       // staging elem col (0..56)
    const int scolb = scole * 2;           // byte col

    f32x4 acc[4][4] = {};

    for (int kt = 0; kt < 8; ++kt) {
        const int k0 = kt * 64;
        #pragma unroll
        for (int r = 0; r < 4; ++r) {
            int row = r * 32 + srow0;
            uint4 va = *(const uint4*)(A + ((long)tm * 128 + row) * DIM + k0 + scole);
            *(uint4*)(ldsA + row * 128 + (scolb ^ ((row & 7) << 4))) = va;
            uint4 vb = *(const uint4*)(Bt + ((long)tn * 128 + row) * DIM + k0 + scole);
            *(uint4*)(ldsB + row * 128 + (scolb ^ ((row & 7) << 4))) = vb;
        }
        __syncthreads();
        #pragma unroll
        for (int kk = 0; kk < 2; ++kk) {
            bf16x8 af[4], bfr[4];
            #pragma unroll
            for (int m = 0; m < 4; ++m) {
                int ar = wr * 64 + m * 16 + lm;
                af[m] = *(const bf16x8*)(ldsA + ar * 128 + ((kk * 64 + lk * 16) ^ ((ar & 7) << 4)));
            }
            #pragma unroll
            for (int n = 0; n < 4; ++n) {
                int br = wc * 64 + n * 16 + lm;
                bfr[n] = *(const bf16x8*)(ldsB + br * 128 + ((kk * 64 + lk * 16) ^ ((br & 7) << 4)));
            }
            #pragma unroll
            for (int m = 0; m < 4; ++m)
                #pragma unroll
                for (int n = 0; n < 4; ++n)
                    acc[m][n] = __builtin_amdgcn_mfma_f32_16x16x32_bf16(af[m], bfr[n], acc[m][n], 0, 0, 0);
        }
        __syncthreads();
    }

    #pragma unroll
    for (int n = 0; n < 4; ++n) {
        int col = tn * 128 + wc * 64 + n * 16 + lm;
        float bc = bias[col];
        float scale = 0.f, shift = 0.f;
        if (EPI == 1) {
            scale = bn_g[col] / sqrtf(bn_var[col] + 1e-5f);
            shift = bn_b[col] - bn_mean[col] * scale;
        }
        #pragma unroll
        for (int m = 0; m < 4; ++m) {
            f32x4 v = acc[m][n];
            #pragma unroll
            for (int r = 0; r < 4; ++r) {
                long row = (long)tm * 128 + wr * 64 + m * 16 + lk * 4 + r;
                float val = fmaxf(v[r] + bc, 0.f);
                if (EPI == 1) val = val * scale + shift;
                outB[row * DIM + col] = f2bf(val);
            }
        }
    }
}

// ---------------- LayerNorm (in-place on hb) + row-norm + hn ----------------
__global__ __launch_bounds__(256) void k_ln(u16* __restrict__ hb,
                                            u16* __restrict__ hn,
                                            const float* __restrict__ g,
                                            const float* __restrict__ b,
                                            float* __restrict__ a0,
                                            float* __restrict__ a1,
                                            float* __restrict__ inv_nrm) {
    int row = blockIdx.x * 4 + (threadIdx.x >> 6);
    int l = threadIdx.x & 63;
    u16* prow = hb + (long)row * DIM + l * 8;
    if (row >= N_NODES) {
        if (row < MPAD) { uint4 z; z.x = z.y = z.z = z.w = 0u; *(uint4*)prow = z; }
        return;
    }
    uint4 v = *(const uint4*)prow;
    float x[8];
    { float2 p;
      p = bfpair(v.x); x[0] = p.x; x[1] = p.y;
      p = bfpair(v.y); x[2] = p.x; x[3] = p.y;
      p = bfpair(v.z); x[4] = p.x; x[5] = p.y;
      p = bfpair(v.w); x[6] = p.x; x[7] = p.y; }
    float s = 0.f, sq = 0.f;
    #pragma unroll
    for (int j = 0; j < 8; ++j) { s += x[j]; sq += x[j] * x[j]; }
    #pragma unroll
    for (int o = 32; o > 0; o >>= 1) { s += __shfl_xor(s, o); sq += __shfl_xor(sq, o); }
    float mean = s * (1.f / DIM);
    float var = sq * (1.f / DIM) - mean * mean;
    float rstd = 1.f / sqrtf(var + 1e-5f);
    float y[8];
    #pragma unroll
    for (int j = 0; j < 8; ++j) {
        int c = l * 8 + j;
        y[j] = (x[j] - mean) * rstd * g[c] + b[c];
    }
    float s2 = 0.f;
    #pragma unroll
    for (int j = 0; j < 8; ++j) s2 += y[j] * y[j];
    s2 = wave_sum(s2);
    float nrm = sqrtf(s2);
    float inv = 1.f / (nrm + 1e-4f);
    ushort4 oh, on;
    oh.x = f2bf(y[0]); oh.y = f2bf(y[1]); oh.z = f2bf(y[2]); oh.w = f2bf(y[3]);
    *(ushort4*)prow = oh;
    oh.x = f2bf(y[4]); oh.y = f2bf(y[5]); oh.z = f2bf(y[6]); oh.w = f2bf(y[7]);
    *(ushort4*)(prow + 4) = oh;
    u16* nrow = hn + (long)row * DIM + l * 8;
    on.x = f2bf(y[0] * inv); on.y = f2bf(y[1] * inv); on.z = f2bf(y[2] * inv); on.w = f2bf(y[3] * inv);
    *(ushort4*)nrow = on;
    on.x = f2bf(y[4] * inv); on.y = f2bf(y[5] * inv); on.z = f2bf(y[6] * inv); on.w = f2bf(y[7] * inv);
    *(ushort4*)(nrow + 4) = on;
    if (l == 0) { a0[row] = y[0]; a1[row] = y[1]; inv_nrm[row] = inv; }
}

// ---------------- per-edge partial dot over dims 2..511, CSR order ----------------
// wave per src node: src row held in registers, loop over its dst rows.
__global__ __launch_bounds__(256) void k_edge_dot(const int* __restrict__ rowptr,
                                                  const int* __restrict__ edst_s,
                                                  const u16* __restrict__ hn,
                                                  float* __restrict__ rest) {
    int node = blockIdx.x * 4 + (threadIdx.x >> 6);
    if (node >= N_NODES) return;
    int l = threadIdx.x & 63;
    int p0 = rowptr[node], p1 = rowptr[node + 1];
    if (p0 == p1) return;
    uint4 sv = *(const uint4*)(hn + (long)node * DIM + l * 8);
    float s_[8];
    { float2 p;
      p = bfpair(sv.x); s_[0] = p.x; s_[1] = p.y;
      p = bfpair(sv.y); s_[2] = p.x; s_[3] = p.y;
      p = bfpair(sv.z); s_[4] = p.x; s_[5] = p.y;
      p = bfpair(sv.w); s_[6] = p.x; s_[7] = p.y; }
    if (l == 0) { s_[0] = 0.f; s_[1] = 0.f; }   // exclude dims 0,1
    for (int p = p0; p < p1; ++p) {
        int d = edst_s[p];
        uint4 dv = *(const uint4*)(hn + (long)d * DIM + l * 8);
        float acc;
        { float2 q = bfpair(dv.x); acc  = s_[0] * q.x + s_[1] * q.y; }
        { float2 q = bfpair(dv.y); acc += s_[2] * q.x + s_[3] * q.y; }
        { float2 q = bfpair(dv.z); acc += s_[4] * q.x + s_[5] * q.y; }
        { float2 q = bfpair(dv.w); acc += s_[6] * q.x + s_[7] * q.y; }
        acc = wave_sum(acc);
        if (l == 0) rest[p] = acc;
    }
}

// ---------------- fused per-layer: segment-sum + rotate ----------------
// reads a0i/a1i (pre-rotation, all nodes), writes a0o/a1o. No atomics.
template<int WRITE_HB>
__global__ __launch_bounds__(256) void k_layer(const int* __restrict__ rowptr,
                                               const int* __restrict__ edst_s,
                                               const float* __restrict__ rest,
                                               const float* __restrict__ a0i,
                                               const float* __restrict__ a1i,
                                               const float* __restrict__ invn,
                                               const float* __restrict__ dinv,
                                               float* __restrict__ a0o,
                                               float* __restrict__ a1o,
                                               u16* __restrict__ hb) {
    int node = blockIdx.x * 4 + (threadIdx.x >> 6);
    if (node >= N_NODES) return;
    int l = threadIdx.x & 63;
    int p0 = rowptr[node], p1 = rowptr[node + 1];
    float x = a0i[node], y = a1i[node];
    float si = invn[node];
    float sa0 = x * si, sa1 = y * si;
    float accum = 0.f;
    for (int p = p0 + l; p < p1; p += 64) {
        int d = edst_s[p];
        float c = rest[p] + (sa0 * a0i[d] + sa1 * a1i[d]) * invn[d];
        c = fminf(1.f, fmaxf(-1.f, c));
        accum += dinv[d] * c;
    }
    accum = wave_sum(accum);
    if (l == 0) {
        float ang = dinv[node] * accum;
        float sn, cs;
        sincosf(ang, &sn, &cs);
        float r0 = cs * x - sn * y;
        float r1 = sn * x + cs * y;
        a0o[node] = r0;
        a1o[node] = r1;
        if (WRITE_HB) {
            hb[(long)node * DIM + 0] = f2bf(r0);
            hb[(long)node * DIM + 1] = f2bf(r1);
        }
    }
}

// ---------------- final: logits (MFMA skinny GEMM) + log_softmax ----------------
__global__ __launch_bounds__(256) void k_final(const u16* __restrict__ zb,
                                               const u16* __restrict__ W2b,
                                               const float* __restrict__ cb2,
                                               float* __restrict__ out) {
    __shared__ char ldsB[48 * 1024];   // 48 KB, XOR-swizzled rows
    const int tid = threadIdx.x;
    #pragma unroll
    for (int i = 0; i < 12; ++i) {
        int unit = i * 256 + tid;          // 3072 x 16B units
        int byte = unit * 16;
        int row = byte >> 10;
        int colb = byte & 1023;
        uint4 v = *(const uint4*)((const char*)W2b + byte);
        *(uint4*)(ldsB + row * 1024 + (colb ^ ((row & 7) << 4))) = v;
    }
    __syncthreads();

    const int l = tid & 63, wid = tid >> 6;
    const int lm = l & 15, lk = l >> 4;
    const long m0 = (long)blockIdx.x * 128 + wid * 32;

    f32x4 acc[2][3] = {};
    for (int kt = 0; kt < 16; ++kt) {
        const int k0 = kt * 32;
        bf16x8 af[2], bfr[3];
        #pragma unroll
        for (int m = 0; m < 2; ++m)
            af[m] = *(const bf16x8*)(zb + (m0 + m * 16 + lm) * DIM + k0 + lk * 8);
        #pragma unroll
        for (int n = 0; n < 3; ++n) {
            int br = n * 16 + lm;
            bfr[n] = *(const bf16x8*)(ldsB + br * 1024 + ((k0 * 2 + lk * 16) ^ ((br & 7) << 4)));
        }
        #pragma unroll
        for (int m = 0; m < 2; ++m)
            #pragma unroll
            for (int n = 0; n < 3; ++n)
                acc[m][n] = __builtin_amdgcn_mfma_f32_16x16x32_bf16(af[m], bfr[n], acc[m][n], 0, 0, 0);
    }

    float bc[3];
    #pragma unroll
    for (int n = 0; n < 3; ++n) {
        int col = n * 16 + lm;
        bc[n] = (col < DOUT) ? cb2[col] : 0.f;
    }

    #pragma unroll
    for (int m = 0; m < 2; ++m) {
        #pragma unroll
        for (int r = 0; r < 4; ++r) {
            long row = m0 + m * 16 + lk * 4 + r;
            float v[3];
            float mv = -1e30f;
            #pragma unroll
            for (int n = 0; n < 3; ++n) {
                int col = n * 16 + lm;
                float t = (col < DOUT) ? (acc[m][n][r] + bc[n]) : -1e30f;
                v[n] = t;
                mv = fmaxf(mv, t);
            }
            #pragma unroll
            for (int o = 8; o > 0; o >>= 1) mv = fmaxf(mv, __shfl_xor(mv, o));
            float es = 0.f;
            #pragma unroll
            for (int n = 0; n < 3; ++n) {
                int col = n * 16 + lm;
                if (col < DOUT) es += expf(v[n] - mv);
            }
            #pragma unroll
            for (int o = 8; o > 0; o >>= 1) es += __shfl_xor(es, o);
            float lse = logf(es);
            if (row < N_NODES) {
                #pragma unroll
                for (int n = 0; n < 3; ++n) {
                    int col = n * 16 + lm;
                    if (col < DOUT) out[row * DOUT + col] = v[n] - mv - lse;
                }
            }
        }
    }
}

extern "C" void kernel_launch(void* const* d_in, const int* in_sizes, int n_in,
                              void* d_out, int out_size, void* d_ws, size_t ws_size,
                              hipStream_t stream) {
    const float* x       = (const float*)d_in[0];
    const int*   esrc    = (const int*)d_in[1];
    const int*   edst    = (const int*)d_in[2];
    const float* W_in    = (const float*)d_in[3];
    const float* b_in    = (const float*)d_in[4];
    const float* ln_g    = (const float*)d_in[5];
    const float* ln_b    = (const float*)d_in[6];
    const float* cW1     = (const float*)d_in[7];
    const float* cb1     = (const float*)d_in[8];
    const float* bn_g    = (const float*)d_in[9];
    const float* bn_b    = (const float*)d_in[10];
    const float* bn_mean = (const float*)d_in[11];
    const float* bn_var  = (const float*)d_in[12];
    const float* cW2     = (const float*)d_in[13];
    const float* cb2     = (const float*)d_in[14];
    float* out = (float*)d_out;

    char* ws = (char*)d_ws;
    size_t off = 0;
    auto take = [&](size_t bytes) -> char* {
        char* p = ws + off;
        off = (off + bytes + 255) & ~(size_t)255;
        return p;
    };
    u16*   xb     = (u16*)take((size_t)MPAD * DIM * 2);   // later reused as zb
    u16*   hb     = (u16*)take((size_t)MPAD * DIM * 2);
    u16*   hn     = (u16*)take((size_t)N_NODES * DIM * 2);
    u16*   WtIn   = (u16*)take((size_t)512 * 512 * 2);
    u16*   W1t    = (u16*)take((size_t)512 * 512 * 2);
    u16*   W2b    = (u16*)take((size_t)48 * 512 * 2);
    int*   deg    = (int*)take((size_t)N_NODES * 4);
    float* dinv   = (float*)take((size_t)N_NODES * 4);
    float* a0A    = (float*)take((size_t)N_NODES * 4);
    float* a1A    = (float*)take((size_t)N_NODES * 4);
    float* a0B    = (float*)take((size_t)N_NODES * 4);
    float* a1B    = (float*)take((size_t)N_NODES * 4);
    float* invn   = (float*)take((size_t)N_NODES * 4);
    float* rest   = (float*)take((size_t)N_EDGES * 4);
    int*   rowptr = (int*)take((size_t)(N_NODES + 1) * 4);
    int*   cnt    = (int*)take((size_t)N_NODES * 4);
    int*   edst_s = (int*)take((size_t)N_EDGES * 4);
    int*   psum   = (int*)take((size_t)NBLK * 4);
    int*   pbase  = (int*)take((size_t)NBLK * 4);
    u16*   zb     = xb;

    hipMemsetAsync(deg, 0, (size_t)N_NODES * 4, stream);

    k_conv_x<<<(MPAD * DIM / 4 + 255) / 256, 256, 0, stream>>>(x, xb);
    k_transpose_bf16<<<dim3(32, 32), dim3(16, 16), 0, stream>>>(W_in, WtIn, 512, 512);
    k_transpose_bf16<<<dim3(32, 32), dim3(16, 16), 0, stream>>>(cW1, W1t, 512, 512);
    k_prep_w2<<<(48 * DIM + 255) / 256, 256, 0, stream>>>(cW2, W2b);

    k_deg<<<N_EDGES / 256, 256, 0, stream>>>(esrc, deg);
    k_dinv<<<(N_NODES + 255) / 256, 256, 0, stream>>>(deg, dinv);
    k_csr_partial<<<NBLK, 256, 0, stream>>>(deg, psum);
    k_csr_base<<<1, 256, 0, stream>>>(psum, pbase, rowptr);
    k_csr_rowptr<<<NBLK, 256, 0, stream>>>(deg, pbase, rowptr, cnt);
    k_scatter<<<N_EDGES / 256, 256, 0, stream>>>(esrc, edst, rowptr, cnt, edst_s);

    k_gemm<0><<<dim3(MPAD / 128, 4), 256, 0, stream>>>(xb, WtIn, hb, b_in,
                                                       nullptr, nullptr, nullptr, nullptr);
    k_ln<<<MPAD / 4, 256, 0, stream>>>(hb, hn, ln_g, ln_b, a0A, a1A, invn);
    k_edge_dot<<<(N_NODES + 3) / 4, 256, 0, stream>>>(rowptr, edst_s, hn, rest);

    k_layer<0><<<(N_NODES + 3) / 4, 256, 0, stream>>>(rowptr, edst_s, rest,
                                                      a0A, a1A, invn, dinv, a0B, a1B, nullptr);
    k_layer<0><<<(N_NODES + 3) / 4, 256, 0, stream>>>(rowptr, edst_s, rest,
                                                      a0B, a1B, invn, dinv, a0A, a1A, nullptr);
    k_layer<1><<<(N_NODES + 3) / 4, 256, 0, stream>>>(rowptr, edst_s, rest,
                                                      a0A, a1A, invn, dinv, a0B, a1B, hb);

    k_gemm<1><<<dim3(MPAD / 128, 4), 256, 0, stream>>>(hb, W1t, zb, cb1,
                                                       bn_g, bn_b, bn_mean, bn_var);
    k_final<<<MPAD / 128, 256, 0, stream>>>(zb, W2b, cb2, out);
}